// Round 19
// baseline (12.638 us; speedup 1.0000x reference)
//
#include <hip/hip_runtime.h>
#include <hip/hip_bf16.h>
#include <math.h>

namespace {
constexpr int Bn = 8192, Pn = 128, Dn = 128;
constexpr int BT = 64, PT = 32;                   // block tile: 64 b x 32 p
constexpr float MAXN = 1.0f - 1e-5f;              // (1-PROJ_EPS)/sqrt(c)
constexpr float CLAMPV = 16.63553233343869f;      // log(2/eps32)
constexpr float SMOOTH = 50.0f;
}

typedef short bf8 __attribute__((ext_vector_type(8)));       // MFMA A/B frag (8 bf16)
typedef float f32x4 __attribute__((ext_vector_type(4)));     // MFMA C/D frag

__device__ __forceinline__ unsigned int bits2(__hip_bfloat162 v) {
  unsigned int u;
  __builtin_memcpy(&u, &v, 4);
  return u;
}

// pairwise 3-level bf16 split via v_cvt_pk_bf16_f32 (RNE, residuals exact fp32)
__device__ __forceinline__ void split3_pair(float f0, float f1,
                                            unsigned int& H, unsigned int& M,
                                            unsigned int& L) {
  __hip_bfloat162 h2 = __float22bfloat162_rn(make_float2(f0, f1));
  float2 fh = __bfloat1622float2(h2);
  __hip_bfloat162 m2 = __float22bfloat162_rn(make_float2(f0 - fh.x, f1 - fh.y));
  float2 fm = __bfloat1622float2(m2);
  __hip_bfloat162 l2 = __float22bfloat162_rn(
      make_float2((f0 - fh.x) - fm.x, (f1 - fh.y) - fm.y));
  H = bits2(h2);
  M = bits2(m2);
  L = bits2(l2);
}

// ---------------- single fused kernel: MFMA bf16x3, wave-owns-quadrant -------
// LDS (16B slots, 4608 = 72 KB):
//   A (x):  level Lv at Lv*1024 + row*16 + (g ^ (row&15)),  row 0..63, g 0..15
//   B (v):  level Lv at 3072 + Lv*512 + p*16 + (g ^ (p&15)), p 0..31
// Stats fully in-wave (butterfly over 8/16 lanes) -> ONE barrier total.
__global__ __launch_bounds__(512, 4)
void fused_kernel(const float* __restrict__ x,
                  const float* __restrict__ weight,
                  const float* __restrict__ bias,
                  float* __restrict__ out) {
  __shared__ float4 lds4[4608];
  __shared__ float opxA[64], fbA[64];
  __shared__ float nbwA[32], iaA[32], soA[32];

  uint4* const L32 = reinterpret_cast<uint4*>(lds4);
  const bf8* const LB = reinterpret_cast<const bf8*>(lds4);

  const int tid = threadIdx.x;
  const int b0 = blockIdx.x * BT;
  const int p0 = blockIdx.y * PT;
  const int rA = tid >> 3, sA = tid & 7;          // x: row 0..63, 16-elem segment
  const int rP = tid >> 4, sP = tid & 15;         // w/b: p-row 0..31, 8-elem granule

  // ---- all global loads issued up front
  float xe[16], we[8], be[8];
  {
    const float* xr = x + (size_t)(b0 + rA) * Dn + sA * 16;
    const float* wr = weight + (size_t)(p0 + rP) * Dn + sP * 8;
    const float* br = bias + (size_t)(p0 + rP) * Dn + sP * 8;
#pragma unroll
    for (int j = 0; j < 4; ++j) {
      float4 q = *reinterpret_cast<const float4*>(xr + 4 * j);
      xe[4 * j] = q.x; xe[4 * j + 1] = q.y; xe[4 * j + 2] = q.z; xe[4 * j + 3] = q.w;
    }
#pragma unroll
    for (int j = 0; j < 2; ++j) {
      float4 qw = *reinterpret_cast<const float4*>(wr + 4 * j);
      float4 qb = *reinterpret_cast<const float4*>(br + 4 * j);
      we[4 * j] = qw.x; we[4 * j + 1] = qw.y; we[4 * j + 2] = qw.z; we[4 * j + 3] = qw.w;
      be[4 * j] = qb.x; be[4 * j + 1] = qb.y; be[4 * j + 2] = qb.z; be[4 * j + 3] = qb.w;
    }
  }

  // ---- phase 1a: x -> 3-level bf16 (packed cvt) + in-wave x2 reduce (8 lanes)
  {
    const int sw = rA & 15;
#pragma unroll
    for (int g = 0; g < 2; ++g) {
      unsigned int HW[4], MW[4], LW[4];
#pragma unroll
      for (int pp = 0; pp < 4; ++pp)
        split3_pair(xe[g * 8 + 2 * pp], xe[g * 8 + 2 * pp + 1],
                    HW[pp], MW[pp], LW[pp]);
      const int slot = rA * 16 + ((2 * sA + g) ^ sw);
      L32[slot]        = make_uint4(HW[0], HW[1], HW[2], HW[3]);
      L32[1024 + slot] = make_uint4(MW[0], MW[1], MW[2], MW[3]);
      L32[2048 + slot] = make_uint4(LW[0], LW[1], LW[2], LW[3]);
    }
    float s2 = 0.f;
#pragma unroll
    for (int e = 0; e < 16; ++e) s2 = fmaf(xe[e], xe[e], s2);
    double xs = (double)s2;                       // f64 island: 1-x2 ~ 2e-5
    xs += __shfl_xor(xs, 1);
    xs += __shfl_xor(xs, 2);
    xs += __shfl_xor(xs, 4);
    if (sA == 0) {
      opxA[rA] = (float)(1.0 + xs);
      fbA[rA] = (float)(2.0 / (1.0 - xs));
    }
  }

  // ---- phase 1b: in-wave p-stats (16 lanes, f32) + v-build + 3-level B writes
  {
    float nb2 = 0.f, bwd = 0.f, w2 = 0.f;
#pragma unroll
    for (int e = 0; e < 8; ++e) {
      nb2 = fmaf(be[e], be[e], nb2);
      bwd = fmaf(be[e], we[e], bwd);
      w2  = fmaf(we[e], we[e], w2);
    }
#pragma unroll
    for (int m = 1; m < 16; m <<= 1) {
      nb2 += __shfl_xor(nb2, m);
      bwd += __shfl_xor(bwd, m);
      w2  += __shfl_xor(w2, m);
    }
    double nb2d = (double)nb2;
    double norm = sqrt(nb2d);
    if (norm < 1e-15) norm = 1e-15;
    double scl = (norm > (double)MAXN) ? (double)MAXN / norm : 1.0;
    double p2 = nb2d * scl * scl;
    const float cxf = (float)(1.0 - p2);          // f64 cancellation island
    const float bwf = (float)(scl * (double)bwd);
    const float k2f = 2.0f * bwf * (float)scl;
    unsigned int VH[4], VM[4], VL[4];
#pragma unroll
    for (int pp = 0; pp < 4; ++pp) {
      float v0 = fmaf(cxf, we[2 * pp], k2f * be[2 * pp]);
      float v1 = fmaf(cxf, we[2 * pp + 1], k2f * be[2 * pp + 1]);
      split3_pair(v0, v1, VH[pp], VM[pp], VL[pp]);
    }
    const int slot = 3072 + rP * 16 + (sP ^ (rP & 15));
    L32[slot]        = make_uint4(VH[0], VH[1], VH[2], VH[3]);
    L32[512 + slot]  = make_uint4(VM[0], VM[1], VM[2], VM[3]);
    L32[1024 + slot] = make_uint4(VL[0], VL[1], VL[2], VL[3]);
    if (sP == 0) {
      float an = cxf * sqrtf(w2);
      if (an < 1e-15f) an = 1e-15f;
      nbwA[rP] = -bwf;
      iaA[rP] = 1.0f / an;
      soA[rP] = 2.0f / cxf * an;                  // lambda_p * a_norm
    }
  }
  __syncthreads();                                // the ONLY barrier

  // ---- phase 2: full-K MFMA; wave = (strip 0..3) x (ptile 0..1); 24 MFMA
  const int wid = tid >> 6, l = tid & 63;
  const int strip = wid & 3, ptile = wid >> 2;
  const int l15 = l & 15;
  const int arow = strip * 16 + l15;
  const int prow = ptile * 16 + l15;
  const int kg = l >> 4;
  f32x4 acc = {0.f, 0.f, 0.f, 0.f};
#pragma unroll
  for (int kc = 0; kc < 4; ++kc) {
    const int ga = (kc * 4 + kg) ^ l15;
    bf8 aH = LB[arow * 16 + ga];
    bf8 aM = LB[1024 + arow * 16 + ga];
    bf8 aL = LB[2048 + arow * 16 + ga];
    bf8 vH = LB[3072 + prow * 16 + ga];
    bf8 vM = LB[3584 + prow * 16 + ga];
    bf8 vL = LB[4096 + prow * 16 + ga];
    // 6 products, small-to-large: ~fp32-accurate
    acc = __builtin_amdgcn_mfma_f32_16x16x32_bf16(aL, vH, acc, 0, 0, 0);
    acc = __builtin_amdgcn_mfma_f32_16x16x32_bf16(aH, vL, acc, 0, 0, 0);
    acc = __builtin_amdgcn_mfma_f32_16x16x32_bf16(aM, vM, acc, 0, 0, 0);
    acc = __builtin_amdgcn_mfma_f32_16x16x32_bf16(aM, vH, acc, 0, 0, 0);
    acc = __builtin_amdgcn_mfma_f32_16x16x32_bf16(aH, vM, acc, 0, 0, 0);
    acc = __builtin_amdgcn_mfma_f32_16x16x32_bf16(aH, vH, acc, 0, 0, 0);
  }

  // ---- epilogue (no barrier; acc private, stat arrays barrier-protected)
  {
    const int pl = ptile * 16 + l15;              // C/D: col = lane&15
    const float nbw = nbwA[pl], iap = iaA[pl], sop = soA[pl];
#pragma unroll
    for (int reg = 0; reg < 4; ++reg) {
      const int brl = strip * 16 + (l >> 4) * 4 + reg;  // C/D: row=(lane>>4)*4+reg
      const float opx = opxA[brl];
      const float fbi = fbA[brl];
      float X = fmaf(opx, nbw, acc[reg]);               // <x,v> - (1+x2)*bw
      float arg = X * fbi * iap;                        // Mobius denominator cancels
      float aa = fabsf(arg);
      float argc;
      if (aa <= CLAMPV - 0.35f) {
        argc = aa;                                      // smooth_clamp == identity
      } else if (aa >= CLAMPV + 0.35f) {
        argc = CLAMPV;                                  // fully clamped (exact)
      } else {
        float z = SMOOTH * (aa - CLAMPV);               // band: softplus correction
        float sp = (fmaxf(z, 0.0f) + log1pf(__expf(-fabsf(z)))) * (1.0f / SMOOTH);
        argc = aa - sp;
      }
      float r = __logf(argc + sqrtf(fmaf(argc, argc, 1.0f)));  // asinh, z>=0
      out[(size_t)(b0 + brl) * Pn + p0 + pl] = copysignf(sop * r, arg);
    }
  }
}

extern "C" void kernel_launch(void* const* d_in, const int* in_sizes, int n_in,
                              void* d_out, int out_size, void* d_ws, size_t ws_size,
                              hipStream_t stream) {
  const float* x = (const float*)d_in[0];
  const float* w = (const float*)d_in[1];
  const float* bias = (const float*)d_in[2];
  float* out = (float*)d_out;

  hipLaunchKernelGGL(fused_kernel, dim3(Bn / BT, Pn / PT), dim3(512), 0, stream,
                     x, w, bias, out);
}

// Round 20
// 11.797 us; speedup vs baseline: 1.0713x; 1.0713x over previous
//
#include <hip/hip_runtime.h>
#include <hip/hip_fp16.h>
#include <math.h>

namespace {
constexpr int Bn = 8192, Pn = 128, Dn = 128;
constexpr int BT = 64, PT = 32;                   // block tile: 64 b x 32 p
constexpr float MAXN = 1.0f - 1e-5f;              // (1-PROJ_EPS)/sqrt(c)
constexpr float CLAMPV = 16.63553233343869f;      // log(2/eps32)
constexpr float SMOOTH = 50.0f;
constexpr float XSC = 256.0f;                     // x pre-scale (f16 normal range)
constexpr float VSC = 64.0f;                      // v pre-scale
constexpr float RSC = 2048.0f;                    // residual scale (2^11)
constexpr float INV_R = 1.0f / 2048.0f;
constexpr float INV_XV = 1.0f / (256.0f * 64.0f);
}

typedef _Float16 h8 __attribute__((ext_vector_type(8)));     // MFMA A/B frag (8 f16)
typedef float f32x4 __attribute__((ext_vector_type(4)));     // MFMA C/D frag

__device__ __forceinline__ unsigned int bitsh2(__half2 v) {
  unsigned int u;
  __builtin_memcpy(&u, &v, 4);
  return u;
}

// 2-level f16 split of a pre-scaled pair; residual scaled by 2^11.
// h = RNE f16(f); m = RNE f16((f-h)*2048). f = (h + m/2048) +- f*2^-22.
__device__ __forceinline__ void split2_pair(float f0, float f1,
                                            unsigned int& H, unsigned int& M) {
  __half2 h2 = __floats2half2_rn(f0, f1);
  float2 fh = __half22float2(h2);
  __half2 m2 = __floats2half2_rn((f0 - fh.x) * RSC, (f1 - fh.y) * RSC);
  H = bitsh2(h2);
  M = bitsh2(m2);
}

// ---------------- single fused kernel: MFMA f16x2 scaled-residual ------------
// LDS (16B slots, 3072 = 48 KB):
//   A-H: [0,1024)  A-M: [1024,2048)  slot = row*16 + (g ^ (row&15))
//   B-H: [2048,2560) B-M: [2560,3072) slot = 2048 + p*16 + (g ^ (p&15))
//   stat scratch overlays B region pre-build. 3 barriers. 3 blocks/CU.
__global__ __launch_bounds__(512, 4)
void fused_kernel(const float* __restrict__ x,
                  const float* __restrict__ weight,
                  const float* __restrict__ bias,
                  float* __restrict__ out) {
  __shared__ float4 lds4[3072];
  __shared__ float psumF[96];
  __shared__ float opxA[64], fbA[64];
  __shared__ float nbwA[32], iaA[32], soA[32];

  uint4* const L32 = reinterpret_cast<uint4*>(lds4);
  const h8* const LH = reinterpret_cast<const h8*>(lds4);
  float* const scp = reinterpret_cast<float*>(lds4 + 2048);  // [stat][seg16 s33][row32]
  float* const scx = scp + 3 * 528;                          // [seg8 s65][row64]

  const int tid = threadIdx.x;
  const int b0 = blockIdx.x * BT;
  const int p0 = blockIdx.y * PT;
  const int rA = tid >> 3, sA = tid & 7;          // x: row 0..63, 16-elem segment
  const int rP = tid >> 4, sP = tid & 15;         // w/b: p-row 0..31, 8-elem granule

  // ---- all global loads issued up front
  float xe[16], we[8], be[8];
  {
    const float* xr = x + (size_t)(b0 + rA) * Dn + sA * 16;
    const float* wr = weight + (size_t)(p0 + rP) * Dn + sP * 8;
    const float* br = bias + (size_t)(p0 + rP) * Dn + sP * 8;
#pragma unroll
    for (int j = 0; j < 4; ++j) {
      float4 q = *reinterpret_cast<const float4*>(xr + 4 * j);
      xe[4 * j] = q.x; xe[4 * j + 1] = q.y; xe[4 * j + 2] = q.z; xe[4 * j + 3] = q.w;
    }
#pragma unroll
    for (int j = 0; j < 2; ++j) {
      float4 qw = *reinterpret_cast<const float4*>(wr + 4 * j);
      float4 qb = *reinterpret_cast<const float4*>(br + 4 * j);
      we[4 * j] = qw.x; we[4 * j + 1] = qw.y; we[4 * j + 2] = qw.z; we[4 * j + 3] = qw.w;
      be[4 * j] = qb.x; be[4 * j + 1] = qb.y; be[4 * j + 2] = qb.z; be[4 * j + 3] = qb.w;
    }
  }

  // ---- phase 1a: x*256 -> 2-level f16 into A region; x2 partial to scratch
  {
    float s2 = 0.f;
#pragma unroll
    for (int e = 0; e < 16; ++e) s2 = fmaf(xe[e], xe[e], s2);
    scx[sA * 65 + rA] = s2;
    const int sw = rA & 15;
#pragma unroll
    for (int g = 0; g < 2; ++g) {
      unsigned int HW[4], MW[4];
#pragma unroll
      for (int pp = 0; pp < 4; ++pp)
        split2_pair(xe[g * 8 + 2 * pp] * XSC, xe[g * 8 + 2 * pp + 1] * XSC,
                    HW[pp], MW[pp]);
      const int slot = rA * 16 + ((2 * sA + g) ^ sw);
      L32[slot]        = make_uint4(HW[0], HW[1], HW[2], HW[3]);
      L32[1024 + slot] = make_uint4(MW[0], MW[1], MW[2], MW[3]);
    }
  }
  // ---- phase 1b: w/b stat partials (f32; p-side has no cancellation)
  {
    float nb2 = 0.f, bwd = 0.f, w2 = 0.f;
#pragma unroll
    for (int e = 0; e < 8; ++e) {
      nb2 = fmaf(be[e], be[e], nb2);
      bwd = fmaf(be[e], we[e], bwd);
      w2  = fmaf(we[e], we[e], w2);
    }
    scp[0 * 528 + sP * 33 + rP] = nb2;
    scp[1 * 528 + sP * 33 + rP] = bwd;
    scp[2 * 528 + sP * 33 + rP] = w2;
  }
  __syncthreads();

  // ---- phase 2: trees
  if (tid < 96) {
    const int stat = tid >> 5, row = tid & 31;
    float s = 0.f;
#pragma unroll
    for (int j = 0; j < 16; ++j) s += scp[stat * 528 + j * 33 + row];
    psumF[stat * 32 + row] = s;
  } else if (tid >= 128 && tid < 192) {
    const int r = tid - 128;
    double s = 0.0;                               // x-side: f64 (1-x2 ~ 2e-5)
#pragma unroll
    for (int j = 0; j < 8; ++j) s += (double)scx[j * 65 + r];
    opxA[r] = (float)(1.0 + s);
    fbA[r] = (float)(2.0 / (1.0 - s));
  }
  __syncthreads();

  // ---- phase 3: v-build (f64 cancellation island) + 2-level f16 B writes
  {
    double nb2 = (double)psumF[rP];
    double bwd = (double)psumF[32 + rP];
    float w2   = psumF[64 + rP];
    double norm = sqrt(nb2);
    if (norm < 1e-15) norm = 1e-15;
    double scl = (norm > (double)MAXN) ? (double)MAXN / norm : 1.0;
    double p2 = nb2 * scl * scl;
    const float cxf = (float)(1.0 - p2);
    const float bwf = (float)(scl * bwd);
    const float k2f = 2.0f * bwf * (float)scl;
    unsigned int VH[4], VM[4];
#pragma unroll
    for (int pp = 0; pp < 4; ++pp) {
      float v0 = fmaf(cxf, we[2 * pp], k2f * be[2 * pp]) * VSC;
      float v1 = fmaf(cxf, we[2 * pp + 1], k2f * be[2 * pp + 1]) * VSC;
      split2_pair(v0, v1, VH[pp], VM[pp]);
    }
    const int slot = 2048 + rP * 16 + (sP ^ (rP & 15));
    L32[slot]       = make_uint4(VH[0], VH[1], VH[2], VH[3]);
    L32[512 + slot] = make_uint4(VM[0], VM[1], VM[2], VM[3]);
    if (sP == 0) {
      float an = cxf * sqrtf(w2);
      if (an < 1e-15f) an = 1e-15f;
      nbwA[rP] = -bwf;
      iaA[rP] = 1.0f / an;
      soA[rP] = 2.0f / cxf * an;                  // lambda_p * a_norm
    }
  }
  __syncthreads();

  // ---- phase 4: full-K MFMA; wave = (strip 0..3) x (ptile 0..1); 16 MFMA
  const int wid = tid >> 6, l = tid & 63;
  const int strip = wid & 3, ptile = wid >> 2;
  const int l15 = l & 15;
  const int arow = strip * 16 + l15;
  const int prow = ptile * 16 + l15;
  const int kg = l >> 4;
  f32x4 a1 = {0.f, 0.f, 0.f, 0.f};                // hh
  f32x4 a2 = {0.f, 0.f, 0.f, 0.f};                // hm + mh  (x 1/2048)
  f32x4 a3 = {0.f, 0.f, 0.f, 0.f};                // mm       (x 1/2048^2)
#pragma unroll
  for (int kc = 0; kc < 4; ++kc) {
    const int ga = (kc * 4 + kg) ^ l15;
    h8 aH = LH[arow * 16 + ga];
    h8 aM = LH[1024 + arow * 16 + ga];
    h8 vH = LH[2048 + prow * 16 + ga];
    h8 vM = LH[2560 + prow * 16 + ga];
    a1 = __builtin_amdgcn_mfma_f32_16x16x32_f16(aH, vH, a1, 0, 0, 0);
    a2 = __builtin_amdgcn_mfma_f32_16x16x32_f16(aH, vM, a2, 0, 0, 0);
    a2 = __builtin_amdgcn_mfma_f32_16x16x32_f16(aM, vH, a2, 0, 0, 0);
    a3 = __builtin_amdgcn_mfma_f32_16x16x32_f16(aM, vM, a3, 0, 0, 0);
  }

  // ---- epilogue (no barrier; accs private, stat arrays barrier-protected)
  {
    const int pl = ptile * 16 + l15;              // C/D: col = lane&15
    const float nbw = nbwA[pl], iap = iaA[pl], sop = soA[pl];
#pragma unroll
    for (int reg = 0; reg < 4; ++reg) {
      const int brl = strip * 16 + (l >> 4) * 4 + reg;  // C/D: row=(lane>>4)*4+reg
      const float opx = opxA[brl];
      const float fbi = fbA[brl];
      float xv = (a1[reg] + (a2[reg] + a3[reg] * INV_R) * INV_R) * INV_XV;
      float X = fmaf(opx, nbw, xv);                     // <x,v> - (1+x2)*bw
      float arg = X * fbi * iap;                        // Mobius denominator cancels
      float aa = fabsf(arg);
      float argc;
      if (aa <= CLAMPV - 0.35f) {
        argc = aa;                                      // smooth_clamp == identity
      } else if (aa >= CLAMPV + 0.35f) {
        argc = CLAMPV;                                  // fully clamped (exact)
      } else {
        float z = SMOOTH * (aa - CLAMPV);               // band: softplus correction
        float sp = (fmaxf(z, 0.0f) + log1pf(__expf(-fabsf(z)))) * (1.0f / SMOOTH);
        argc = aa - sp;
      }
      float r = __logf(argc + sqrtf(fmaf(argc, argc, 1.0f)));  // asinh, z>=0
      out[(size_t)(b0 + brl) * Pn + p0 + pl] = copysignf(sop * r, arg);
    }
  }
}

extern "C" void kernel_launch(void* const* d_in, const int* in_sizes, int n_in,
                              void* d_out, int out_size, void* d_ws, size_t ws_size,
                              hipStream_t stream) {
  const float* x = (const float*)d_in[0];
  const float* w = (const float*)d_in[1];
  const float* bias = (const float*)d_in[2];
  float* out = (float*)d_out;

  hipLaunchKernelGGL(fused_kernel, dim3(Bn / BT, Pn / PT), dim3(512), 0, stream,
                     x, w, bias, out);
}

// Round 21
// 11.754 us; speedup vs baseline: 1.0752x; 1.0037x over previous
//
#include <hip/hip_runtime.h>
#include <hip/hip_fp16.h>
#include <math.h>

namespace {
constexpr int Bn = 8192, Pn = 128, Dn = 128;
constexpr int BT = 64, PT = 32;                   // block tile: 64 b x 32 p
constexpr float MAXN = 1.0f - 1e-5f;              // (1-PROJ_EPS)/sqrt(c)
constexpr float CLAMPV = 16.63553233343869f;      // log(2/eps32)
constexpr float SMOOTH = 50.0f;
constexpr float XSC = 256.0f;                     // x pre-scale (f16 normal range)
constexpr float VSC = 64.0f;                      // v pre-scale
constexpr float RSC = 2048.0f;                    // residual scale (2^11)
constexpr float INV_R = 1.0f / 2048.0f;
constexpr float INV_XV = 1.0f / (256.0f * 64.0f);
}

typedef _Float16 h8 __attribute__((ext_vector_type(8)));     // MFMA A/B frag (8 f16)
typedef float f32x4 __attribute__((ext_vector_type(4)));     // MFMA C/D frag

__device__ __forceinline__ unsigned int bitsh2(__half2 v) {
  unsigned int u;
  __builtin_memcpy(&u, &v, 4);
  return u;
}

// 2-level f16 split of a pre-scaled pair; residual scaled by 2^11.
// h = RNE f16(f); m = RNE f16((f-h)*2048). f = (h + m/2048) +- f*2^-22.
__device__ __forceinline__ void split2_pair(float f0, float f1,
                                            unsigned int& H, unsigned int& M) {
  __half2 h2 = __floats2half2_rn(f0, f1);
  float2 fh = __half22float2(h2);
  __half2 m2 = __floats2half2_rn((f0 - fh.x) * RSC, (f1 - fh.y) * RSC);
  H = bitsh2(h2);
  M = bitsh2(m2);
}

// ---------------- single fused kernel: MFMA f16x2 scaled-residual ------------
// LDS (16B slots, 3072 = 48 KB -> 3 blocks/CU with launch_bounds(512,6)):
//   A-H: [0,1024)  A-M: [1024,2048)  slot = row*16 + (g ^ (row&15))
//   B-H: [2048,2560) B-M: [2560,3072) slot = 2048 + p*16 + (g ^ (p&15))
//   stat scratch overlays B region pre-build. 3 barriers.
__global__ __launch_bounds__(512, 6)
void fused_kernel(const float* __restrict__ x,
                  const float* __restrict__ weight,
                  const float* __restrict__ bias,
                  float* __restrict__ out) {
  __shared__ float4 lds4[3072];
  __shared__ float psumF[96];
  __shared__ float opxA[64], fbA[64];
  __shared__ float nbwA[32], iaA[32], soA[32];

  uint4* const L32 = reinterpret_cast<uint4*>(lds4);
  const h8* const LH = reinterpret_cast<const h8*>(lds4);
  float* const scp = reinterpret_cast<float*>(lds4 + 2048);  // [stat][seg16 s33][row32]
  float* const scx = scp + 3 * 528;                          // [seg8 s65][row64]

  const int tid = threadIdx.x;
  const int b0 = blockIdx.x * BT;
  const int p0 = blockIdx.y * PT;
  const int rA = tid >> 3, sA = tid & 7;          // x: row 0..63, 16-elem segment
  const int rP = tid >> 4, sP = tid & 15;         // w/b: p-row 0..31, 8-elem granule

  // ---- all global loads issued up front
  float xe[16], we[8], be[8];
  {
    const float* xr = x + (size_t)(b0 + rA) * Dn + sA * 16;
    const float* wr = weight + (size_t)(p0 + rP) * Dn + sP * 8;
    const float* br = bias + (size_t)(p0 + rP) * Dn + sP * 8;
#pragma unroll
    for (int j = 0; j < 4; ++j) {
      float4 q = *reinterpret_cast<const float4*>(xr + 4 * j);
      xe[4 * j] = q.x; xe[4 * j + 1] = q.y; xe[4 * j + 2] = q.z; xe[4 * j + 3] = q.w;
    }
#pragma unroll
    for (int j = 0; j < 2; ++j) {
      float4 qw = *reinterpret_cast<const float4*>(wr + 4 * j);
      float4 qb = *reinterpret_cast<const float4*>(br + 4 * j);
      we[4 * j] = qw.x; we[4 * j + 1] = qw.y; we[4 * j + 2] = qw.z; we[4 * j + 3] = qw.w;
      be[4 * j] = qb.x; be[4 * j + 1] = qb.y; be[4 * j + 2] = qb.z; be[4 * j + 3] = qb.w;
    }
  }

  // ---- phase 1a: x*256 -> 2-level f16 into A region; x2 partial to scratch
  {
    float s2 = 0.f;
#pragma unroll
    for (int e = 0; e < 16; ++e) s2 = fmaf(xe[e], xe[e], s2);
    scx[sA * 65 + rA] = s2;
    const int sw = rA & 15;
#pragma unroll
    for (int g = 0; g < 2; ++g) {
      unsigned int HW[4], MW[4];
#pragma unroll
      for (int pp = 0; pp < 4; ++pp)
        split2_pair(xe[g * 8 + 2 * pp] * XSC, xe[g * 8 + 2 * pp + 1] * XSC,
                    HW[pp], MW[pp]);
      const int slot = rA * 16 + ((2 * sA + g) ^ sw);
      L32[slot]        = make_uint4(HW[0], HW[1], HW[2], HW[3]);
      L32[1024 + slot] = make_uint4(MW[0], MW[1], MW[2], MW[3]);
    }
  }
  // ---- phase 1b: w/b stat partials (f32; p-side has no cancellation)
  {
    float nb2 = 0.f, bwd = 0.f, w2 = 0.f;
#pragma unroll
    for (int e = 0; e < 8; ++e) {
      nb2 = fmaf(be[e], be[e], nb2);
      bwd = fmaf(be[e], we[e], bwd);
      w2  = fmaf(we[e], we[e], w2);
    }
    scp[0 * 528 + sP * 33 + rP] = nb2;
    scp[1 * 528 + sP * 33 + rP] = bwd;
    scp[2 * 528 + sP * 33 + rP] = w2;
  }
  __syncthreads();

  // ---- phase 2: trees
  if (tid < 96) {
    const int stat = tid >> 5, row = tid & 31;
    float s = 0.f;
#pragma unroll
    for (int j = 0; j < 16; ++j) s += scp[stat * 528 + j * 33 + row];
    psumF[stat * 32 + row] = s;
  } else if (tid >= 128 && tid < 192) {
    const int r = tid - 128;
    double s = 0.0;                               // x-side: f64 (1-x2 ~ 2e-5)
#pragma unroll
    for (int j = 0; j < 8; ++j) s += (double)scx[j * 65 + r];
    opxA[r] = (float)(1.0 + s);
    fbA[r] = (float)(2.0 / (1.0 - s));
  }
  __syncthreads();

  // ---- phase 3: v-build (f64 cancellation island) + 2-level f16 B writes
  {
    double nb2 = (double)psumF[rP];
    double bwd = (double)psumF[32 + rP];
    float w2   = psumF[64 + rP];
    double norm = sqrt(nb2);
    if (norm < 1e-15) norm = 1e-15;
    double scl = (norm > (double)MAXN) ? (double)MAXN / norm : 1.0;
    double p2 = nb2 * scl * scl;
    const float cxf = (float)(1.0 - p2);
    const float bwf = (float)(scl * bwd);
    const float k2f = 2.0f * bwf * (float)scl;
    unsigned int VH[4], VM[4];
#pragma unroll
    for (int pp = 0; pp < 4; ++pp) {
      float v0 = fmaf(cxf, we[2 * pp], k2f * be[2 * pp]) * VSC;
      float v1 = fmaf(cxf, we[2 * pp + 1], k2f * be[2 * pp + 1]) * VSC;
      split2_pair(v0, v1, VH[pp], VM[pp]);
    }
    const int slot = 2048 + rP * 16 + (sP ^ (rP & 15));
    L32[slot]       = make_uint4(VH[0], VH[1], VH[2], VH[3]);
    L32[512 + slot] = make_uint4(VM[0], VM[1], VM[2], VM[3]);
    if (sP == 0) {
      float an = cxf * sqrtf(w2);
      if (an < 1e-15f) an = 1e-15f;
      nbwA[rP] = -bwf;
      iaA[rP] = 1.0f / an;
      soA[rP] = 2.0f / cxf * an;                  // lambda_p * a_norm
    }
  }
  __syncthreads();

  // ---- phase 4: full-K MFMA; wave = (strip 0..3) x (ptile 0..1); 16 MFMA
  const int wid = tid >> 6, l = tid & 63;
  const int strip = wid & 3, ptile = wid >> 2;
  const int l15 = l & 15;
  const int arow = strip * 16 + l15;
  const int prow = ptile * 16 + l15;
  const int kg = l >> 4;
  f32x4 a1 = {0.f, 0.f, 0.f, 0.f};                // hh
  f32x4 a2 = {0.f, 0.f, 0.f, 0.f};                // hm + mh  (x 1/2048)
  f32x4 a3 = {0.f, 0.f, 0.f, 0.f};                // mm       (x 1/2048^2)
#pragma unroll
  for (int kc = 0; kc < 4; ++kc) {
    const int ga = (kc * 4 + kg) ^ l15;
    h8 aH = LH[arow * 16 + ga];
    h8 aM = LH[1024 + arow * 16 + ga];
    h8 vH = LH[2048 + prow * 16 + ga];
    h8 vM = LH[2560 + prow * 16 + ga];
    a1 = __builtin_amdgcn_mfma_f32_16x16x32_f16(aH, vH, a1, 0, 0, 0);
    a2 = __builtin_amdgcn_mfma_f32_16x16x32_f16(aH, vM, a2, 0, 0, 0);
    a2 = __builtin_amdgcn_mfma_f32_16x16x32_f16(aM, vH, a2, 0, 0, 0);
    a3 = __builtin_amdgcn_mfma_f32_16x16x32_f16(aM, vM, a3, 0, 0, 0);
  }

  // ---- epilogue (no barrier; accs private, stat arrays barrier-protected)
  {
    const int pl = ptile * 16 + l15;              // C/D: col = lane&15
    const float nbw = nbwA[pl], iap = iaA[pl], sop = soA[pl];
#pragma unroll
    for (int reg = 0; reg < 4; ++reg) {
      const int brl = strip * 16 + (l >> 4) * 4 + reg;  // C/D: row=(lane>>4)*4+reg
      const float opx = opxA[brl];
      const float fbi = fbA[brl];
      float xv = (a1[reg] + (a2[reg] + a3[reg] * INV_R) * INV_R) * INV_XV;
      float X = fmaf(opx, nbw, xv);                     // <x,v> - (1+x2)*bw
      float arg = X * fbi * iap;                        // Mobius denominator cancels
      float aa = fabsf(arg);
      float argc;
      if (aa <= CLAMPV - 0.35f) {
        argc = aa;                                      // smooth_clamp == identity
      } else if (aa >= CLAMPV + 0.35f) {
        argc = CLAMPV;                                  // fully clamped (exact)
      } else {
        float z = SMOOTH * (aa - CLAMPV);               // band: softplus correction
        float sp = (fmaxf(z, 0.0f) + log1pf(__expf(-fabsf(z)))) * (1.0f / SMOOTH);
        argc = aa - sp;
      }
      float r = __logf(argc + sqrtf(fmaf(argc, argc, 1.0f)));  // asinh, z>=0
      out[(size_t)(b0 + brl) * Pn + p0 + pl] = copysignf(sop * r, arg);
    }
  }
}

extern "C" void kernel_launch(void* const* d_in, const int* in_sizes, int n_in,
                              void* d_out, int out_size, void* d_ws, size_t ws_size,
                              hipStream_t stream) {
  const float* x = (const float*)d_in[0];
  const float* w = (const float*)d_in[1];
  const float* bias = (const float*)d_in[2];
  float* out = (float*)d_out;

  hipLaunchKernelGGL(fused_kernel, dim3(Bn / BT, Pn / PT), dim3(512), 0, stream,
                     x, w, bias, out);
}